// Round 1
// baseline (884.494 us; speedup 1.0000x reference)
//
#include <hip/hip_runtime.h>

// GraphSAGE_13993003450942 — bf16-MFMA pipeline
// CSR build -> mean-agg -> conv GEMM (fused l/r) x2 -> fused edge-MLP GEMM.

typedef float f32x4 __attribute__((ext_vector_type(4)));
typedef __bf16 bf16x8 __attribute__((ext_vector_type(8)));

__device__ __forceinline__ unsigned short f2b(float f) {
    unsigned u = __float_as_uint(f);
    u = u + 0x7fffu + ((u >> 16) & 1u);   // RNE
    return (unsigned short)(u >> 16);
}
__device__ __forceinline__ float b2f(unsigned short s) {
    return __uint_as_float(((unsigned)s) << 16);
}

// ---------------- CSR build ----------------

__global__ void k_count(const int* __restrict__ dst, int* __restrict__ cnt, int E) {
    int e = blockIdx.x * 256 + threadIdx.x;
    if (e < E) atomicAdd(&cnt[dst[e]], 1);
}

// single block, 1024 threads: exclusive scan of cnt -> row_ptr, cursor (in-place over cnt)
__global__ __launch_bounds__(1024) void k_scan(int* __restrict__ cnt_cursor,
                                               int* __restrict__ row_ptr, int n) {
    __shared__ int wsum[16];
    __shared__ int carry;
    int t = threadIdx.x, lane = t & 63, w = t >> 6;
    if (t == 0) carry = 0;
    __syncthreads();
    int nch = (n + 1023) >> 10;
    for (int ch = 0; ch < nch; ++ch) {
        int i = (ch << 10) + t;
        int v = (i < n) ? cnt_cursor[i] : 0;
        int s = v;
        #pragma unroll
        for (int off = 1; off < 64; off <<= 1) {
            int u = __shfl_up(s, off);
            if (lane >= off) s += u;
        }
        if (lane == 63) wsum[w] = s;
        __syncthreads();
        int wpre = 0;
        for (int j = 0; j < w; ++j) wpre += wsum[j];
        int incl = s + wpre;
        int base = carry;
        if (i < n) { int ex = base + incl - v; row_ptr[i] = ex; cnt_cursor[i] = ex; }
        __syncthreads();
        if (t == 1023) carry = base + incl;
    }
    __syncthreads();
    if (t == 0) row_ptr[n] = carry;
}

__global__ void k_scatter(const int* __restrict__ src, const int* __restrict__ dst,
                          int* __restrict__ cursor, int* __restrict__ bucket, int E) {
    int e = blockIdx.x * 256 + threadIdx.x;
    if (e < E) {
        int p = atomicAdd(&cursor[dst[e]], 1);
        bucket[p] = src[e];
    }
}

// ---------------- conversions ----------------

// Wc1: [8][256][32] (chunks 0-3 = Wl1, 4-7 = Wr1), Wc2: [16][256][32], W1ck: [17][256][32] (pad K 528->544)
__global__ void k_convert_weights(const float* __restrict__ Wl1, const float* __restrict__ Wr1,
                                  const float* __restrict__ Wl2, const float* __restrict__ Wr2,
                                  const float* __restrict__ W1,
                                  unsigned short* __restrict__ Wc1,
                                  unsigned short* __restrict__ Wc2,
                                  unsigned short* __restrict__ W1ck) {
    int idx = blockIdx.x * 256 + threadIdx.x;
    if (idx < 65536) {
        int c = idx >> 13, j = (idx >> 5) & 255, kk = idx & 31;
        float v = (c < 4) ? Wl1[j * 128 + c * 32 + kk] : Wr1[j * 128 + (c - 4) * 32 + kk];
        Wc1[idx] = f2b(v);
    } else if (idx < 65536 + 131072) {
        int i2 = idx - 65536;
        int c = i2 >> 13, j = (i2 >> 5) & 255, kk = i2 & 31;
        float v = (c < 8) ? Wl2[j * 256 + c * 32 + kk] : Wr2[j * 256 + (c - 8) * 32 + kk];
        Wc2[i2] = f2b(v);
    } else if (idx < 65536 + 131072 + 139264) {
        int i3 = idx - 65536 - 131072;
        int c = i3 >> 13, j = (i3 >> 5) & 255, kk = i3 & 31;
        int col = c * 32 + kk;
        W1ck[i3] = (col < 528) ? f2b(W1[j * 528 + col]) : (unsigned short)0;
    }
}

__global__ void k_f2b_copy(const float* __restrict__ in, unsigned short* __restrict__ out, int n) {
    int i = blockIdx.x * 256 + threadIdx.x;
    if (i < n) out[i] = f2b(in[i]);
}

// ---------------- aggregation (mean over in-neighbors) ----------------

// x fp32 [N][128] -> agg bf16 [N][128]; one wave per node, lane handles 2 cols
__global__ __launch_bounds__(256) void k_agg_x(const float* __restrict__ x,
                                               const int* __restrict__ row_ptr,
                                               const int* __restrict__ bucket,
                                               unsigned short* __restrict__ agg, int Nn) {
    int node = blockIdx.x * 4 + (threadIdx.x >> 6);
    if (node >= Nn) return;
    int lane = threadIdx.x & 63;
    int beg = row_ptr[node], end = row_ptr[node + 1];
    float s0 = 0.f, s1 = 0.f;
    const float* xp = x + lane * 2;
    for (int e = beg; e < end; ++e) {
        const float2 v = *reinterpret_cast<const float2*>(xp + (size_t)bucket[e] * 128);
        s0 += v.x; s1 += v.y;
    }
    int d = end - beg;
    float sc = 1.0f / (float)(d > 1 ? d : 1);
    unsigned o = (unsigned)f2b(s0 * sc) | ((unsigned)f2b(s1 * sc) << 16);
    *reinterpret_cast<unsigned*>(agg + (size_t)node * 128 + lane * 2) = o;
}

// h bf16 [N][256] -> agg bf16 [N][256]; lane handles 4 cols
__global__ __launch_bounds__(256) void k_agg_h(const unsigned short* __restrict__ h,
                                               const int* __restrict__ row_ptr,
                                               const int* __restrict__ bucket,
                                               unsigned short* __restrict__ agg, int Nn) {
    int node = blockIdx.x * 4 + (threadIdx.x >> 6);
    if (node >= Nn) return;
    int lane = threadIdx.x & 63;
    int beg = row_ptr[node], end = row_ptr[node + 1];
    float s0 = 0.f, s1 = 0.f, s2 = 0.f, s3 = 0.f;
    const unsigned short* hp = h + lane * 4;
    for (int e = beg; e < end; ++e) {
        const uint2 v = *reinterpret_cast<const uint2*>(hp + (size_t)bucket[e] * 256);
        s0 += b2f((unsigned short)(v.x & 0xffffu));
        s1 += b2f((unsigned short)(v.x >> 16));
        s2 += b2f((unsigned short)(v.y & 0xffffu));
        s3 += b2f((unsigned short)(v.y >> 16));
    }
    int d = end - beg;
    float sc = 1.0f / (float)(d > 1 ? d : 1);
    uint2 o;
    o.x = (unsigned)f2b(s0 * sc) | ((unsigned)f2b(s1 * sc) << 16);
    o.y = (unsigned)f2b(s2 * sc) | ((unsigned)f2b(s3 * sc) << 16);
    *reinterpret_cast<uint2*>(agg + (size_t)node * 256 + lane * 4) = o;
}

// ---------------- conv GEMM: H = relu(bias + Aagg@Wl^T + Aself@Wr^T), bf16 out ----------------
// 256 thr = 4 waves (2x2), tile 128 nodes x 128 cols, K = 2*F via chunk-major Wck [2F/32][256][32]

__global__ __launch_bounds__(256) void k_conv_gemm(const unsigned short* __restrict__ Aagg,
                                                   const unsigned short* __restrict__ Aself,
                                                   const unsigned short* __restrict__ Wck,
                                                   const float* __restrict__ bias,
                                                   unsigned short* __restrict__ Hout,
                                                   int Nn, int F) {
    __shared__ __align__(16) unsigned short zt[128 * 32];
    __shared__ __align__(16) unsigned short wt[128 * 32];
    const int t = threadIdx.x;
    const int lane = t & 63, w = t >> 6;
    const int wm = w >> 1, wn = w & 1;
    const int node0 = blockIdx.x * 128;
    const int colh = blockIdx.y;          // 0/1 -> 128-col half
    const int half = F >> 5, nchunks = F >> 4;

    f32x4 acc[4][4];
    #pragma unroll
    for (int i = 0; i < 4; ++i)
        #pragma unroll
        for (int j = 0; j < 4; ++j) acc[i][j] = (f32x4){0.f, 0.f, 0.f, 0.f};

    for (int c = 0; c < nchunks; ++c) {
        __syncthreads();
        const unsigned short* Asrc = (c < half) ? Aagg : Aself;
        const int ccol = ((c < half) ? c : c - half) * 32;
        #pragma unroll
        for (int p = 0; p < 2; ++p) {
            int fc = t + p * 256;
            int row = fc >> 2, seg = fc & 3;
            int node = node0 + row; if (node >= Nn) node = Nn - 1;
            uint4 v = *reinterpret_cast<const uint4*>(Asrc + (size_t)node * F + ccol + seg * 8);
            *reinterpret_cast<uint4*>(&zt[row * 32 + seg * 8]) = v;
        }
        const unsigned short* Wsrc = Wck + ((size_t)c * 256 + colh * 128) * 32;
        #pragma unroll
        for (int p = 0; p < 2; ++p) {
            int fc = t + p * 256;
            *reinterpret_cast<uint4*>(&wt[fc * 8]) = *reinterpret_cast<const uint4*>(Wsrc + fc * 8);
        }
        __syncthreads();
        bf16x8 a[4], b[4];
        #pragma unroll
        for (int mi = 0; mi < 4; ++mi)
            a[mi] = *reinterpret_cast<const bf16x8*>(&zt[(wm * 64 + mi * 16 + (lane & 15)) * 32 + (lane >> 4) * 8]);
        #pragma unroll
        for (int ni = 0; ni < 4; ++ni)
            b[ni] = *reinterpret_cast<const bf16x8*>(&wt[(wn * 64 + ni * 16 + (lane & 15)) * 32 + (lane >> 4) * 8]);
        #pragma unroll
        for (int mi = 0; mi < 4; ++mi)
            #pragma unroll
            for (int ni = 0; ni < 4; ++ni)
                acc[mi][ni] = __builtin_amdgcn_mfma_f32_16x16x32_bf16(a[mi], b[ni], acc[mi][ni], 0, 0, 0);
    }

    #pragma unroll
    for (int mi = 0; mi < 4; ++mi)
        #pragma unroll
        for (int ni = 0; ni < 4; ++ni) {
            int col = colh * 128 + wn * 64 + ni * 16 + (lane & 15);
            float bia = bias[col];
            #pragma unroll
            for (int r = 0; r < 4; ++r) {
                int row = node0 + wm * 64 + mi * 16 + ((lane >> 4) << 2) + r;
                if (row < Nn) {
                    float v = acc[mi][ni][r] + bia;
                    v = v > 0.f ? v : 0.f;
                    Hout[(size_t)row * 256 + col] = f2b(v);
                }
            }
        }
}

// ---------------- edge MLP: out = logexp + b2 + relu(z@W1^T + b1)@W2 ----------------
// 256 thr = 4 waves (1x4), tile 64 edges x 256 outs, K = 544 (h_u 256 | h_v 256 | attr 16 pad 32)

__global__ __launch_bounds__(256) void k_mlp(const unsigned short* __restrict__ h2b,
                                             const float* __restrict__ attr,
                                             const int* __restrict__ eu,
                                             const int* __restrict__ ev,
                                             const unsigned short* __restrict__ W1ck,
                                             const float* __restrict__ b1,
                                             const float* __restrict__ W2,
                                             const float* __restrict__ b2,
                                             const float* __restrict__ logexp,
                                             float* __restrict__ out, int P) {
    __shared__ __align__(16) unsigned short zt[64 * 32];
    __shared__ __align__(16) unsigned short wt[256 * 32];
    __shared__ float spart[4][64];
    const int t = threadIdx.x;
    const int lane = t & 63, w = t >> 6;   // w = col group (64 cols each)
    const int row0 = blockIdx.x * 64;

    f32x4 acc[4][4];
    #pragma unroll
    for (int i = 0; i < 4; ++i)
        #pragma unroll
        for (int j = 0; j < 4; ++j) acc[i][j] = (f32x4){0.f, 0.f, 0.f, 0.f};

    const int srow = t >> 2, sseg = t & 3;
    int rg = row0 + srow; if (rg >= P) rg = P - 1;
    const int ue = eu[rg], ve = ev[rg];

    for (int c = 0; c < 17; ++c) {
        __syncthreads();
        {
            int col = c * 32 + sseg * 8;
            uint4 v;
            if (col < 256) {
                v = *reinterpret_cast<const uint4*>(h2b + (size_t)ue * 256 + col);
            } else if (col < 512) {
                v = *reinterpret_cast<const uint4*>(h2b + (size_t)ve * 256 + (col - 256));
            } else {
                int j0 = col - 512;
                unsigned r0 = 0, r1 = 0, r2 = 0, r3 = 0;
                if (j0 < 16) {
                    const float4 f0 = *reinterpret_cast<const float4*>(attr + (size_t)rg * 16 + j0);
                    const float4 f1 = *reinterpret_cast<const float4*>(attr + (size_t)rg * 16 + j0 + 4);
                    r0 = (unsigned)f2b(f0.x) | ((unsigned)f2b(f0.y) << 16);
                    r1 = (unsigned)f2b(f0.z) | ((unsigned)f2b(f0.w) << 16);
                    r2 = (unsigned)f2b(f1.x) | ((unsigned)f2b(f1.y) << 16);
                    r3 = (unsigned)f2b(f1.z) | ((unsigned)f2b(f1.w) << 16);
                }
                v.x = r0; v.y = r1; v.z = r2; v.w = r3;
            }
            *reinterpret_cast<uint4*>(&zt[srow * 32 + sseg * 8]) = v;
        }
        const unsigned short* Wsrc = W1ck + (size_t)c * 8192;
        #pragma unroll
        for (int p = 0; p < 4; ++p) {
            int fc = t + p * 256;
            *reinterpret_cast<uint4*>(&wt[fc * 8]) = *reinterpret_cast<const uint4*>(Wsrc + fc * 8);
        }
        __syncthreads();
        bf16x8 a[4], b[4];
        #pragma unroll
        for (int mi = 0; mi < 4; ++mi)
            a[mi] = *reinterpret_cast<const bf16x8*>(&zt[(mi * 16 + (lane & 15)) * 32 + (lane >> 4) * 8]);
        #pragma unroll
        for (int ni = 0; ni < 4; ++ni)
            b[ni] = *reinterpret_cast<const bf16x8*>(&wt[(w * 64 + ni * 16 + (lane & 15)) * 32 + (lane >> 4) * 8]);
        #pragma unroll
        for (int mi = 0; mi < 4; ++mi)
            #pragma unroll
            for (int ni = 0; ni < 4; ++ni)
                acc[mi][ni] = __builtin_amdgcn_mfma_f32_16x16x32_bf16(a[mi], b[ni], acc[mi][ni], 0, 0, 0);
    }

    // fused epilogue: s_row = sum_col relu(y + b1[col]) * W2[col]
    float b1v[4], w2v[4];
    #pragma unroll
    for (int ni = 0; ni < 4; ++ni) {
        int col = w * 64 + ni * 16 + (lane & 15);
        b1v[ni] = b1[col];
        w2v[ni] = W2[col];
    }
    const int q = lane >> 4;
    #pragma unroll
    for (int mi = 0; mi < 4; ++mi)
        #pragma unroll
        for (int r = 0; r < 4; ++r) {
            float v = 0.f;
            #pragma unroll
            for (int ni = 0; ni < 4; ++ni) {
                float y = acc[mi][ni][r] + b1v[ni];
                v += (y > 0.f ? y : 0.f) * w2v[ni];
            }
            v += __shfl_xor(v, 1);
            v += __shfl_xor(v, 2);
            v += __shfl_xor(v, 4);
            v += __shfl_xor(v, 8);
            if ((lane & 15) == 0) spart[w][mi * 16 + q * 4 + r] = v;
        }
    __syncthreads();
    if (t < 64) {
        int rr = row0 + t;
        if (rr < P)
            out[rr] = logexp[rr] + b2[0] + spart[0][t] + spart[1][t] + spart[2][t] + spart[3][t];
    }
}

// ---------------- launch ----------------

extern "C" void kernel_launch(void* const* d_in, const int* in_sizes, int n_in,
                              void* d_out, int out_size, void* d_ws, size_t ws_size,
                              hipStream_t stream) {
    const float* x      = (const float*)d_in[0];
    const int*   eidx   = (const int*)d_in[1];
    const int*   eu     = (const int*)d_in[2];
    const int*   ev     = (const int*)d_in[3];
    const float* attr   = (const float*)d_in[4];
    const float* logexp = (const float*)d_in[5];
    const float* Wl1    = (const float*)d_in[6];
    const float* bl1    = (const float*)d_in[7];
    const float* Wr1    = (const float*)d_in[8];
    const float* Wl2    = (const float*)d_in[9];
    const float* bl2    = (const float*)d_in[10];
    const float* Wr2    = (const float*)d_in[11];
    const float* W1     = (const float*)d_in[12];
    const float* b1     = (const float*)d_in[13];
    const float* W2     = (const float*)d_in[14];
    const float* b2     = (const float*)d_in[15];
    float* out = (float*)d_out;

    const int N = in_sizes[0] / 128;
    const int E = in_sizes[1] / 2;
    const int P = in_sizes[2];
    const int* src = eidx;
    const int* dst = eidx + E;

    char* ws = (char*)d_ws;
    size_t off = 0;
    auto alloc = [&](size_t bytes) -> void* {
        off = (off + 255) & ~(size_t)255;
        void* p = ws + off;
        off += bytes;
        return p;
    };
    int* row_ptr = (int*)alloc((size_t)(N + 1) * 4);
    int* cursor  = (int*)alloc((size_t)N * 4);
    int* bucket  = (int*)alloc((size_t)E * 4);
    unsigned short* xb   = (unsigned short*)alloc((size_t)N * 128 * 2);
    unsigned short* agg1 = (unsigned short*)alloc((size_t)N * 128 * 2);
    unsigned short* h1   = (unsigned short*)alloc((size_t)N * 256 * 2);
    unsigned short* agg2 = (unsigned short*)alloc((size_t)N * 256 * 2);
    unsigned short* h2   = (unsigned short*)alloc((size_t)N * 256 * 2);
    unsigned short* Wc1  = (unsigned short*)alloc((size_t)65536 * 2);
    unsigned short* Wc2  = (unsigned short*)alloc((size_t)131072 * 2);
    unsigned short* W1ck = (unsigned short*)alloc((size_t)139264 * 2);

    hipMemsetAsync(cursor, 0, (size_t)N * 4, stream);
    k_count<<<(E + 255) / 256, 256, 0, stream>>>(dst, cursor, E);
    k_scan<<<1, 1024, 0, stream>>>(cursor, row_ptr, N);
    k_scatter<<<(E + 255) / 256, 256, 0, stream>>>(src, dst, cursor, bucket, E);
    k_convert_weights<<<(65536 + 131072 + 139264 + 255) / 256, 256, 0, stream>>>(
        Wl1, Wr1, Wl2, Wr2, W1, Wc1, Wc2, W1ck);
    k_f2b_copy<<<(N * 128 + 255) / 256, 256, 0, stream>>>(x, xb, N * 128);

    k_agg_x<<<(N + 3) / 4, 256, 0, stream>>>(x, row_ptr, bucket, agg1, N);
    dim3 gconv((N + 127) / 128, 2);
    k_conv_gemm<<<gconv, 256, 0, stream>>>(agg1, xb, Wc1, bl1, h1, N, 128);
    k_agg_h<<<(N + 3) / 4, 256, 0, stream>>>(h1, row_ptr, bucket, agg2, N);
    k_conv_gemm<<<gconv, 256, 0, stream>>>(agg2, h1, Wc2, bl2, h2, N, 256);
    k_mlp<<<(P + 63) / 64, 256, 0, stream>>>(h2, attr, eu, ev, W1ck, b1, W2, b2, logexp, out, P);
}

// Round 2
// 603.675 us; speedup vs baseline: 1.4652x; 1.4652x over previous
//
#include <hip/hip_runtime.h>

// GraphSAGE_13993003450942 — bf16-MFMA pipeline, round 2:
//  - k_mlp: double-buffered LDS + register prefetch (gather latency hidden)
//  - XOR granule swizzle on all GEMM LDS tiles (kills 8-way read conflicts)
//  - aggregations: bf16 gather, 16B/lane, multi-edge ILP, shfl reduce

typedef float f32x4 __attribute__((ext_vector_type(4)));
typedef __bf16 bf16x8 __attribute__((ext_vector_type(8)));

__device__ __forceinline__ unsigned short f2b(float f) {
    unsigned u = __float_as_uint(f);
    u = u + 0x7fffu + ((u >> 16) & 1u);   // RNE
    return (unsigned short)(u >> 16);
}
__device__ __forceinline__ float b2f(unsigned short s) {
    return __uint_as_float(((unsigned)s) << 16);
}
// LDS granule swizzle: logical 16B-granule g of 64B row r -> physical granule
__device__ __forceinline__ int swz(int r, int g) { return (g + (r >> 1)) & 3; }

// ---------------- CSR build ----------------

__global__ void k_count(const int* __restrict__ dst, int* __restrict__ cnt, int E) {
    int e = blockIdx.x * 256 + threadIdx.x;
    if (e < E) atomicAdd(&cnt[dst[e]], 1);
}

__global__ __launch_bounds__(1024) void k_scan(int* __restrict__ cnt_cursor,
                                               int* __restrict__ row_ptr, int n) {
    __shared__ int wsum[16];
    __shared__ int carry;
    int t = threadIdx.x, lane = t & 63, w = t >> 6;
    if (t == 0) carry = 0;
    __syncthreads();
    int nch = (n + 1023) >> 10;
    for (int ch = 0; ch < nch; ++ch) {
        int i = (ch << 10) + t;
        int v = (i < n) ? cnt_cursor[i] : 0;
        int s = v;
        #pragma unroll
        for (int off = 1; off < 64; off <<= 1) {
            int u = __shfl_up(s, off);
            if (lane >= off) s += u;
        }
        if (lane == 63) wsum[w] = s;
        __syncthreads();
        int wpre = 0;
        for (int j = 0; j < w; ++j) wpre += wsum[j];
        int incl = s + wpre;
        int base = carry;
        if (i < n) { int ex = base + incl - v; row_ptr[i] = ex; cnt_cursor[i] = ex; }
        __syncthreads();
        if (t == 1023) carry = base + incl;
    }
    __syncthreads();
    if (t == 0) row_ptr[n] = carry;
}

__global__ void k_scatter(const int* __restrict__ src, const int* __restrict__ dst,
                          int* __restrict__ cursor, int* __restrict__ bucket, int E) {
    int e = blockIdx.x * 256 + threadIdx.x;
    if (e < E) {
        int p = atomicAdd(&cursor[dst[e]], 1);
        bucket[p] = src[e];
    }
}

// ---------------- conversions ----------------

__global__ void k_convert_weights(const float* __restrict__ Wl1, const float* __restrict__ Wr1,
                                  const float* __restrict__ Wl2, const float* __restrict__ Wr2,
                                  const float* __restrict__ W1,
                                  unsigned short* __restrict__ Wc1,
                                  unsigned short* __restrict__ Wc2,
                                  unsigned short* __restrict__ W1ck) {
    int idx = blockIdx.x * 256 + threadIdx.x;
    if (idx < 65536) {
        int c = idx >> 13, j = (idx >> 5) & 255, kk = idx & 31;
        float v = (c < 4) ? Wl1[j * 128 + c * 32 + kk] : Wr1[j * 128 + (c - 4) * 32 + kk];
        Wc1[idx] = f2b(v);
    } else if (idx < 65536 + 131072) {
        int i2 = idx - 65536;
        int c = i2 >> 13, j = (i2 >> 5) & 255, kk = i2 & 31;
        float v = (c < 8) ? Wl2[j * 256 + c * 32 + kk] : Wr2[j * 256 + (c - 8) * 32 + kk];
        Wc2[i2] = f2b(v);
    } else if (idx < 65536 + 131072 + 139264) {
        int i3 = idx - 65536 - 131072;
        int c = i3 >> 13, j = (i3 >> 5) & 255, kk = i3 & 31;
        int col = c * 32 + kk;
        W1ck[i3] = (col < 528) ? f2b(W1[j * 528 + col]) : (unsigned short)0;
    }
}

__global__ void k_f2b_copy(const float* __restrict__ in, unsigned short* __restrict__ out, int n) {
    int i = blockIdx.x * 256 + threadIdx.x;
    if (i < n) out[i] = f2b(in[i]);
}

// ---------------- aggregation (mean over in-neighbors) ----------------

__device__ __forceinline__ void acc8(uint4 v, float* s) {
    s[0] += b2f((unsigned short)(v.x & 0xffffu)); s[1] += b2f((unsigned short)(v.x >> 16));
    s[2] += b2f((unsigned short)(v.y & 0xffffu)); s[3] += b2f((unsigned short)(v.y >> 16));
    s[4] += b2f((unsigned short)(v.z & 0xffffu)); s[5] += b2f((unsigned short)(v.z >> 16));
    s[6] += b2f((unsigned short)(v.w & 0xffffu)); s[7] += b2f((unsigned short)(v.w >> 16));
}

// xb bf16 [N][128] -> agg bf16 [N][128]; one wave/node; 4 edge-subgroups x 16 lanes x 16B
__global__ __launch_bounds__(256) void k_agg_x(const unsigned short* __restrict__ xb,
                                               const int* __restrict__ row_ptr,
                                               const int* __restrict__ bucket,
                                               unsigned short* __restrict__ agg, int Nn) {
    int node = blockIdx.x * 4 + (threadIdx.x >> 6);
    if (node >= Nn) return;
    int lane = threadIdx.x & 63;
    int g = lane >> 4, c = lane & 15;       // subgroup, col granule (8 cols)
    int beg = row_ptr[node], end = row_ptr[node + 1];
    float s[8] = {0.f,0.f,0.f,0.f,0.f,0.f,0.f,0.f};
    const unsigned short* xp = xb + c * 8;
    int e = beg + g;
    for (; e + 4 < end; e += 8) {
        uint4 v0 = *reinterpret_cast<const uint4*>(xp + (size_t)bucket[e] * 128);
        uint4 v1 = *reinterpret_cast<const uint4*>(xp + (size_t)bucket[e + 4] * 128);
        acc8(v0, s); acc8(v1, s);
    }
    if (e < end)
        acc8(*reinterpret_cast<const uint4*>(xp + (size_t)bucket[e] * 128), s);
    #pragma unroll
    for (int j = 0; j < 8; ++j) {
        s[j] += __shfl_xor(s[j], 16);
        s[j] += __shfl_xor(s[j], 32);
    }
    if (g == 0) {
        int d = end - beg;
        float sc = 1.0f / (float)(d > 1 ? d : 1);
        uint4 o;
        o.x = (unsigned)f2b(s[0]*sc) | ((unsigned)f2b(s[1]*sc) << 16);
        o.y = (unsigned)f2b(s[2]*sc) | ((unsigned)f2b(s[3]*sc) << 16);
        o.z = (unsigned)f2b(s[4]*sc) | ((unsigned)f2b(s[5]*sc) << 16);
        o.w = (unsigned)f2b(s[6]*sc) | ((unsigned)f2b(s[7]*sc) << 16);
        *reinterpret_cast<uint4*>(agg + (size_t)node * 128 + c * 8) = o;
    }
}

// h bf16 [N][256] -> agg bf16 [N][256]; one wave/node; 2 edge-subgroups x 32 lanes x 16B
__global__ __launch_bounds__(256) void k_agg_h(const unsigned short* __restrict__ h,
                                               const int* __restrict__ row_ptr,
                                               const int* __restrict__ bucket,
                                               unsigned short* __restrict__ agg, int Nn) {
    int node = blockIdx.x * 4 + (threadIdx.x >> 6);
    if (node >= Nn) return;
    int lane = threadIdx.x & 63;
    int g = lane >> 5, c = lane & 31;
    int beg = row_ptr[node], end = row_ptr[node + 1];
    float s[8] = {0.f,0.f,0.f,0.f,0.f,0.f,0.f,0.f};
    const unsigned short* hp = h + c * 8;
    int e = beg + g;
    for (; e + 2 < end; e += 4) {
        uint4 v0 = *reinterpret_cast<const uint4*>(hp + (size_t)bucket[e] * 256);
        uint4 v1 = *reinterpret_cast<const uint4*>(hp + (size_t)bucket[e + 2] * 256);
        acc8(v0, s); acc8(v1, s);
    }
    if (e < end)
        acc8(*reinterpret_cast<const uint4*>(hp + (size_t)bucket[e] * 256), s);
    #pragma unroll
    for (int j = 0; j < 8; ++j) s[j] += __shfl_xor(s[j], 32);
    if (g == 0) {
        int d = end - beg;
        float sc = 1.0f / (float)(d > 1 ? d : 1);
        uint4 o;
        o.x = (unsigned)f2b(s[0]*sc) | ((unsigned)f2b(s[1]*sc) << 16);
        o.y = (unsigned)f2b(s[2]*sc) | ((unsigned)f2b(s[3]*sc) << 16);
        o.z = (unsigned)f2b(s[4]*sc) | ((unsigned)f2b(s[5]*sc) << 16);
        o.w = (unsigned)f2b(s[6]*sc) | ((unsigned)f2b(s[7]*sc) << 16);
        *reinterpret_cast<uint4*>(agg + (size_t)node * 256 + c * 8) = o;
    }
}

// ---------------- conv GEMM: H = relu(bias + Aagg@Wl^T + Aself@Wr^T), bf16 out ----------------

__global__ __launch_bounds__(256) void k_conv_gemm(const unsigned short* __restrict__ Aagg,
                                                   const unsigned short* __restrict__ Aself,
                                                   const unsigned short* __restrict__ Wck,
                                                   const float* __restrict__ bias,
                                                   unsigned short* __restrict__ Hout,
                                                   int Nn, int F) {
    __shared__ __align__(16) unsigned short zt[128 * 32];
    __shared__ __align__(16) unsigned short wt[128 * 32];
    const int t = threadIdx.x;
    const int lane = t & 63, w = t >> 6;
    const int wm = w >> 1, wn = w & 1;
    const int node0 = blockIdx.x * 128;
    const int colh = blockIdx.y;
    const int half = F >> 5, nchunks = F >> 4;

    f32x4 acc[4][4];
    #pragma unroll
    for (int i = 0; i < 4; ++i)
        #pragma unroll
        for (int j = 0; j < 4; ++j) acc[i][j] = (f32x4){0.f, 0.f, 0.f, 0.f};

    for (int c = 0; c < nchunks; ++c) {
        __syncthreads();
        const unsigned short* Asrc = (c < half) ? Aagg : Aself;
        const int ccol = ((c < half) ? c : c - half) * 32;
        #pragma unroll
        for (int p = 0; p < 2; ++p) {
            int fc = t + p * 256;
            int row = fc >> 2, seg = fc & 3;
            int node = node0 + row; if (node >= Nn) node = Nn - 1;
            uint4 v = *reinterpret_cast<const uint4*>(Asrc + (size_t)node * F + ccol + seg * 8);
            *reinterpret_cast<uint4*>(&zt[row * 32 + swz(row, seg) * 8]) = v;
        }
        const unsigned short* Wsrc = Wck + ((size_t)c * 256 + colh * 128) * 32;
        #pragma unroll
        for (int p = 0; p < 2; ++p) {
            int fc = t + p * 256;
            int row = fc >> 2, seg = fc & 3;
            *reinterpret_cast<uint4*>(&wt[row * 32 + swz(row, seg) * 8]) =
                *reinterpret_cast<const uint4*>(Wsrc + fc * 8);
        }
        __syncthreads();
        bf16x8 a[4], b[4];
        const int q = lane >> 4;
        #pragma unroll
        for (int mi = 0; mi < 4; ++mi) {
            int R = wm * 64 + mi * 16 + (lane & 15);
            a[mi] = *reinterpret_cast<const bf16x8*>(&zt[R * 32 + swz(R, q) * 8]);
        }
        #pragma unroll
        for (int ni = 0; ni < 4; ++ni) {
            int R = wn * 64 + ni * 16 + (lane & 15);
            b[ni] = *reinterpret_cast<const bf16x8*>(&wt[R * 32 + swz(R, q) * 8]);
        }
        #pragma unroll
        for (int mi = 0; mi < 4; ++mi)
            #pragma unroll
            for (int ni = 0; ni < 4; ++ni)
                acc[mi][ni] = __builtin_amdgcn_mfma_f32_16x16x32_bf16(a[mi], b[ni], acc[mi][ni], 0, 0, 0);
    }

    #pragma unroll
    for (int mi = 0; mi < 4; ++mi)
        #pragma unroll
        for (int ni = 0; ni < 4; ++ni) {
            int col = colh * 128 + wn * 64 + ni * 16 + (lane & 15);
            float bia = bias[col];
            #pragma unroll
            for (int r = 0; r < 4; ++r) {
                int row = node0 + wm * 64 + mi * 16 + ((lane >> 4) << 2) + r;
                if (row < Nn) {
                    float v = acc[mi][ni][r] + bia;
                    v = v > 0.f ? v : 0.f;
                    Hout[(size_t)row * 256 + col] = f2b(v);
                }
            }
        }
}

// ---------------- edge MLP: out = logexp + b2 + relu(z@W1^T + b1)@W2 ----------------
// double-buffered LDS, register prefetch; tile 64 edges x 256 cols, K = 17 chunks of 32

__global__ __launch_bounds__(256, 3) void k_mlp(const unsigned short* __restrict__ h2b,
                                                const float* __restrict__ attr,
                                                const int* __restrict__ eu,
                                                const int* __restrict__ ev,
                                                const unsigned short* __restrict__ W1ck,
                                                const float* __restrict__ b1,
                                                const float* __restrict__ W2,
                                                const float* __restrict__ b2,
                                                const float* __restrict__ logexp,
                                                float* __restrict__ out, int P) {
    __shared__ __align__(16) unsigned short zt[2][64 * 32];
    __shared__ __align__(16) unsigned short wt[2][256 * 32];
    __shared__ float spart[4][64];
    const int t = threadIdx.x;
    const int lane = t & 63, w = t >> 6;
    const int row0 = blockIdx.x * 64;

    f32x4 acc[4][4];
    #pragma unroll
    for (int i = 0; i < 4; ++i)
        #pragma unroll
        for (int j = 0; j < 4; ++j) acc[i][j] = (f32x4){0.f, 0.f, 0.f, 0.f};

    const int srow = t >> 2, sseg = t & 3;
    int rg = row0 + srow; if (rg >= P) rg = P - 1;
    const int ue = eu[rg], ve = ev[rg];

    auto load_z = [&](int c) -> uint4 {
        int col = c * 32 + sseg * 8;
        uint4 v;
        if (col < 256) {
            v = *reinterpret_cast<const uint4*>(h2b + (size_t)ue * 256 + col);
        } else if (col < 512) {
            v = *reinterpret_cast<const uint4*>(h2b + (size_t)ve * 256 + (col - 256));
        } else {
            int j0 = col - 512;
            unsigned r0 = 0, r1 = 0, r2 = 0, r3 = 0;
            if (j0 < 16) {
                const float4 f0 = *reinterpret_cast<const float4*>(attr + (size_t)rg * 16 + j0);
                const float4 f1 = *reinterpret_cast<const float4*>(attr + (size_t)rg * 16 + j0 + 4);
                r0 = (unsigned)f2b(f0.x) | ((unsigned)f2b(f0.y) << 16);
                r1 = (unsigned)f2b(f0.z) | ((unsigned)f2b(f0.w) << 16);
                r2 = (unsigned)f2b(f1.x) | ((unsigned)f2b(f1.y) << 16);
                r3 = (unsigned)f2b(f1.z) | ((unsigned)f2b(f1.w) << 16);
            }
            v.x = r0; v.y = r1; v.z = r2; v.w = r3;
        }
        return v;
    };

    uint4 pz = load_z(0);
    uint4 pw[4];
    #pragma unroll
    for (int p = 0; p < 4; ++p)
        pw[p] = *reinterpret_cast<const uint4*>(W1ck + (size_t)0 * 8192 + (t + p * 256) * 8);

    // stage chunk 0 into buffer 0
    *reinterpret_cast<uint4*>(&zt[0][srow * 32 + swz(srow, sseg) * 8]) = pz;
    #pragma unroll
    for (int p = 0; p < 4; ++p) {
        int fc = t + p * 256, row = fc >> 2, seg = fc & 3;
        *reinterpret_cast<uint4*>(&wt[0][row * 32 + swz(row, seg) * 8]) = pw[p];
    }

    int buf = 0;
    for (int c = 0; c < 17; ++c) {
        __syncthreads();
        const bool more = (c + 1 < 17);
        if (more) {
            pz = load_z(c + 1);
            #pragma unroll
            for (int p = 0; p < 4; ++p)
                pw[p] = *reinterpret_cast<const uint4*>(W1ck + (size_t)(c + 1) * 8192 + (t + p * 256) * 8);
        }
        bf16x8 a[4], b[4];
        const int q = lane >> 4;
        #pragma unroll
        for (int mi = 0; mi < 4; ++mi) {
            int R = mi * 16 + (lane & 15);
            a[mi] = *reinterpret_cast<const bf16x8*>(&zt[buf][R * 32 + swz(R, q) * 8]);
        }
        #pragma unroll
        for (int ni = 0; ni < 4; ++ni) {
            int R = w * 64 + ni * 16 + (lane & 15);
            b[ni] = *reinterpret_cast<const bf16x8*>(&wt[buf][R * 32 + swz(R, q) * 8]);
        }
        #pragma unroll
        for (int mi = 0; mi < 4; ++mi)
            #pragma unroll
            for (int ni = 0; ni < 4; ++ni)
                acc[mi][ni] = __builtin_amdgcn_mfma_f32_16x16x32_bf16(a[mi], b[ni], acc[mi][ni], 0, 0, 0);
        if (more) {
            *reinterpret_cast<uint4*>(&zt[buf ^ 1][srow * 32 + swz(srow, sseg) * 8]) = pz;
            #pragma unroll
            for (int p = 0; p < 4; ++p) {
                int fc = t + p * 256, row = fc >> 2, seg = fc & 3;
                *reinterpret_cast<uint4*>(&wt[buf ^ 1][row * 32 + swz(row, seg) * 8]) = pw[p];
            }
        }
        buf ^= 1;
    }

    float b1v[4], w2v[4];
    #pragma unroll
    for (int ni = 0; ni < 4; ++ni) {
        int col = w * 64 + ni * 16 + (lane & 15);
        b1v[ni] = b1[col];
        w2v[ni] = W2[col];
    }
    const int q = lane >> 4;
    #pragma unroll
    for (int mi = 0; mi < 4; ++mi)
        #pragma unroll
        for (int r = 0; r < 4; ++r) {
            float v = 0.f;
            #pragma unroll
            for (int ni = 0; ni < 4; ++ni) {
                float y = acc[mi][ni][r] + b1v[ni];
                v += (y > 0.f ? y : 0.f) * w2v[ni];
            }
            v += __shfl_xor(v, 1);
            v += __shfl_xor(v, 2);
            v += __shfl_xor(v, 4);
            v += __shfl_xor(v, 8);
            if ((lane & 15) == 0) spart[w][mi * 16 + q * 4 + r] = v;
        }
    __syncthreads();
    if (t < 64) {
        int rr = row0 + t;
        if (rr < P)
            out[rr] = logexp[rr] + b2[0] + spart[0][t] + spart[1][t] + spart[2][t] + spart[3][t];
    }
}

// ---------------- launch ----------------

extern "C" void kernel_launch(void* const* d_in, const int* in_sizes, int n_in,
                              void* d_out, int out_size, void* d_ws, size_t ws_size,
                              hipStream_t stream) {
    const float* x      = (const float*)d_in[0];
    const int*   eidx   = (const int*)d_in[1];
    const int*   eu     = (const int*)d_in[2];
    const int*   ev     = (const int*)d_in[3];
    const float* attr   = (const float*)d_in[4];
    const float* logexp = (const float*)d_in[5];
    const float* Wl1    = (const float*)d_in[6];
    const float* bl1    = (const float*)d_in[7];
    const float* Wr1    = (const float*)d_in[8];
    const float* Wl2    = (const float*)d_in[9];
    const float* bl2    = (const float*)d_in[10];
    const float* Wr2    = (const float*)d_in[11];
    const float* W1     = (const float*)d_in[12];
    const float* b1     = (const float*)d_in[13];
    const float* W2     = (const float*)d_in[14];
    const float* b2     = (const float*)d_in[15];
    float* out = (float*)d_out;

    const int N = in_sizes[0] / 128;
    const int E = in_sizes[1] / 2;
    const int P = in_sizes[2];
    const int* src = eidx;
    const int* dst = eidx + E;

    char* ws = (char*)d_ws;
    size_t off = 0;
    auto alloc = [&](size_t bytes) -> void* {
        off = (off + 255) & ~(size_t)255;
        void* p = ws + off;
        off += bytes;
        return p;
    };
    int* row_ptr = (int*)alloc((size_t)(N + 1) * 4);
    int* cursor  = (int*)alloc((size_t)N * 4);
    int* bucket  = (int*)alloc((size_t)E * 4);
    unsigned short* xb   = (unsigned short*)alloc((size_t)N * 128 * 2);
    unsigned short* agg1 = (unsigned short*)alloc((size_t)N * 128 * 2);
    unsigned short* h1   = (unsigned short*)alloc((size_t)N * 256 * 2);
    unsigned short* agg2 = (unsigned short*)alloc((size_t)N * 256 * 2);
    unsigned short* h2   = (unsigned short*)alloc((size_t)N * 256 * 2);
    unsigned short* Wc1  = (unsigned short*)alloc((size_t)65536 * 2);
    unsigned short* Wc2  = (unsigned short*)alloc((size_t)131072 * 2);
    unsigned short* W1ck = (unsigned short*)alloc((size_t)139264 * 2);

    hipMemsetAsync(cursor, 0, (size_t)N * 4, stream);
    k_count<<<(E + 255) / 256, 256, 0, stream>>>(dst, cursor, E);
    k_scan<<<1, 1024, 0, stream>>>(cursor, row_ptr, N);
    k_scatter<<<(E + 255) / 256, 256, 0, stream>>>(src, dst, cursor, bucket, E);
    k_convert_weights<<<(65536 + 131072 + 139264 + 255) / 256, 256, 0, stream>>>(
        Wl1, Wr1, Wl2, Wr2, W1, Wc1, Wc2, W1ck);
    k_f2b_copy<<<(N * 128 + 255) / 256, 256, 0, stream>>>(x, xb, N * 128);

    k_agg_x<<<(N + 3) / 4, 256, 0, stream>>>(xb, row_ptr, bucket, agg1, N);
    dim3 gconv((N + 127) / 128, 2);
    k_conv_gemm<<<gconv, 256, 0, stream>>>(agg1, xb, Wc1, bl1, h1, N, 128);
    k_agg_h<<<(N + 3) / 4, 256, 0, stream>>>(h1, row_ptr, bucket, agg2, N);
    k_conv_gemm<<<gconv, 256, 0, stream>>>(agg2, h1, Wc2, bl2, h2, N, 256);
    k_mlp<<<(P + 63) / 64, 256, 0, stream>>>(h2, attr, eu, ev, W1ck, b1, W2, b2, logexp, out, P);
}

// Round 3
// 600.259 us; speedup vs baseline: 1.4735x; 1.0057x over previous
//
#include <hip/hip_runtime.h>

// GraphSAGE_13993003450942 — round 3: factor edge MLP through nodes.
// y_e = Gu[u] + Gv[v] + (W1a@attr_e + b1);  Gu/Gv = h2 @ W1u/W1v^T (node GEMM).
// Edge kernel: per-wave 16 edges, attr-term via MFMA (b1 folded as attr[16]=1 row),
// Gu/Gv gathered per-lane in C-layout, fused relu·W2 reduction.

typedef float f32x4 __attribute__((ext_vector_type(4)));
typedef __bf16 bf16x8 __attribute__((ext_vector_type(8)));

__device__ __forceinline__ unsigned short f2b(float f) {
    unsigned u = __float_as_uint(f);
    u = u + 0x7fffu + ((u >> 16) & 1u);   // RNE
    return (unsigned short)(u >> 16);
}
__device__ __forceinline__ float b2f(unsigned short s) {
    return __uint_as_float(((unsigned)s) << 16);
}
__device__ __forceinline__ int swz(int r, int g) { return (g + (r >> 1)) & 3; }

// ---------------- CSR build ----------------

__global__ void k_count(const int* __restrict__ dst, int* __restrict__ cnt, int E) {
    int e = blockIdx.x * 256 + threadIdx.x;
    if (e < E) atomicAdd(&cnt[dst[e]], 1);
}

__global__ __launch_bounds__(1024) void k_scan(int* __restrict__ cnt_cursor,
                                               int* __restrict__ row_ptr, int n) {
    __shared__ int wsum[16];
    __shared__ int carry;
    int t = threadIdx.x, lane = t & 63, w = t >> 6;
    if (t == 0) carry = 0;
    __syncthreads();
    int nch = (n + 1023) >> 10;
    for (int ch = 0; ch < nch; ++ch) {
        int i = (ch << 10) + t;
        int v = (i < n) ? cnt_cursor[i] : 0;
        int s = v;
        #pragma unroll
        for (int off = 1; off < 64; off <<= 1) {
            int u = __shfl_up(s, off);
            if (lane >= off) s += u;
        }
        if (lane == 63) wsum[w] = s;
        __syncthreads();
        int wpre = 0;
        for (int j = 0; j < w; ++j) wpre += wsum[j];
        int incl = s + wpre;
        int base = carry;
        if (i < n) { int ex = base + incl - v; row_ptr[i] = ex; cnt_cursor[i] = ex; }
        __syncthreads();
        if (t == 1023) carry = base + incl;
    }
    __syncthreads();
    if (t == 0) row_ptr[n] = carry;
}

__global__ void k_scatter(const int* __restrict__ src, const int* __restrict__ dst,
                          int* __restrict__ cursor, int* __restrict__ bucket, int E) {
    int e = blockIdx.x * 256 + threadIdx.x;
    if (e < E) {
        int p = atomicAdd(&cursor[dst[e]], 1);
        bucket[p] = src[e];
    }
}

// ---------------- conversions / weight repack ----------------
// Wc1 [8][256][32] (Wl1|Wr1), Wc2 [16][256][32] (Wl2|Wr2),
// W1g [8][512][32] (rows 0-255: W1[:,0:256]; rows 256-511: W1[:,256:512]),
// WaF [16][64][8] bf16 A-fragments of W1a_pad (k<16: W1[:,512+k]; k==16: b1; else 0)

__global__ void k_convert_weights(const float* __restrict__ Wl1, const float* __restrict__ Wr1,
                                  const float* __restrict__ Wl2, const float* __restrict__ Wr2,
                                  const float* __restrict__ W1, const float* __restrict__ b1,
                                  unsigned short* __restrict__ Wc1,
                                  unsigned short* __restrict__ Wc2,
                                  unsigned short* __restrict__ W1g,
                                  unsigned short* __restrict__ WaF) {
    int idx = blockIdx.x * 256 + threadIdx.x;
    if (idx < 65536) {
        int c = idx >> 13, j = (idx >> 5) & 255, kk = idx & 31;
        float v = (c < 4) ? Wl1[j * 128 + c * 32 + kk] : Wr1[j * 128 + (c - 4) * 32 + kk];
        Wc1[idx] = f2b(v);
    } else if (idx < 65536 + 131072) {
        int i2 = idx - 65536;
        int c = i2 >> 13, j = (i2 >> 5) & 255, kk = i2 & 31;
        float v = (c < 8) ? Wl2[j * 256 + c * 32 + kk] : Wr2[j * 256 + (c - 8) * 32 + kk];
        Wc2[i2] = f2b(v);
    } else if (idx < 65536 + 131072 + 131072) {
        int i3 = idx - 65536 - 131072;
        int c = i3 >> 14, j = (i3 >> 5) & 511, kk = i3 & 31;
        float v = (j < 256) ? W1[(size_t)j * 528 + c * 32 + kk]
                            : W1[(size_t)(j - 256) * 528 + 256 + c * 32 + kk];
        W1g[i3] = f2b(v);
    } else if (idx < 65536 + 131072 + 131072 + 8192) {
        int i4 = idx - 65536 - 131072 - 131072;
        int mi = i4 >> 9, l = (i4 >> 3) & 63, j = i4 & 7;
        int m = mi * 16 + (l & 15);
        int k = (l >> 4) * 8 + j;
        float v = (k < 16) ? W1[(size_t)m * 528 + 512 + k] : (k == 16 ? b1[m] : 0.f);
        WaF[i4] = f2b(v);
    }
}

__global__ void k_f2b_copy(const float* __restrict__ in, unsigned short* __restrict__ out, int n) {
    int i = blockIdx.x * 256 + threadIdx.x;
    if (i < n) out[i] = f2b(in[i]);
}

// ---------------- aggregation (mean over in-neighbors) ----------------

__device__ __forceinline__ void acc8(uint4 v, float* s) {
    s[0] += b2f((unsigned short)(v.x & 0xffffu)); s[1] += b2f((unsigned short)(v.x >> 16));
    s[2] += b2f((unsigned short)(v.y & 0xffffu)); s[3] += b2f((unsigned short)(v.y >> 16));
    s[4] += b2f((unsigned short)(v.z & 0xffffu)); s[5] += b2f((unsigned short)(v.z >> 16));
    s[6] += b2f((unsigned short)(v.w & 0xffffu)); s[7] += b2f((unsigned short)(v.w >> 16));
}

__global__ __launch_bounds__(256) void k_agg_x(const unsigned short* __restrict__ xb,
                                               const int* __restrict__ row_ptr,
                                               const int* __restrict__ bucket,
                                               unsigned short* __restrict__ agg, int Nn) {
    int node = blockIdx.x * 4 + (threadIdx.x >> 6);
    if (node >= Nn) return;
    int lane = threadIdx.x & 63;
    int g = lane >> 4, c = lane & 15;
    int beg = row_ptr[node], end = row_ptr[node + 1];
    float s[8] = {0.f,0.f,0.f,0.f,0.f,0.f,0.f,0.f};
    const unsigned short* xp = xb + c * 8;
    int e = beg + g;
    for (; e + 4 < end; e += 8) {
        uint4 v0 = *reinterpret_cast<const uint4*>(xp + (size_t)bucket[e] * 128);
        uint4 v1 = *reinterpret_cast<const uint4*>(xp + (size_t)bucket[e + 4] * 128);
        acc8(v0, s); acc8(v1, s);
    }
    if (e < end)
        acc8(*reinterpret_cast<const uint4*>(xp + (size_t)bucket[e] * 128), s);
    #pragma unroll
    for (int j = 0; j < 8; ++j) {
        s[j] += __shfl_xor(s[j], 16);
        s[j] += __shfl_xor(s[j], 32);
    }
    if (g == 0) {
        int d = end - beg;
        float sc = 1.0f / (float)(d > 1 ? d : 1);
        uint4 o;
        o.x = (unsigned)f2b(s[0]*sc) | ((unsigned)f2b(s[1]*sc) << 16);
        o.y = (unsigned)f2b(s[2]*sc) | ((unsigned)f2b(s[3]*sc) << 16);
        o.z = (unsigned)f2b(s[4]*sc) | ((unsigned)f2b(s[5]*sc) << 16);
        o.w = (unsigned)f2b(s[6]*sc) | ((unsigned)f2b(s[7]*sc) << 16);
        *reinterpret_cast<uint4*>(agg + (size_t)node * 128 + c * 8) = o;
    }
}

__global__ __launch_bounds__(256) void k_agg_h(const unsigned short* __restrict__ h,
                                               const int* __restrict__ row_ptr,
                                               const int* __restrict__ bucket,
                                               unsigned short* __restrict__ agg, int Nn) {
    int node = blockIdx.x * 4 + (threadIdx.x >> 6);
    if (node >= Nn) return;
    int lane = threadIdx.x & 63;
    int g = lane >> 5, c = lane & 31;
    int beg = row_ptr[node], end = row_ptr[node + 1];
    float s[8] = {0.f,0.f,0.f,0.f,0.f,0.f,0.f,0.f};
    const unsigned short* hp = h + c * 8;
    int e = beg + g;
    for (; e + 2 < end; e += 4) {
        uint4 v0 = *reinterpret_cast<const uint4*>(hp + (size_t)bucket[e] * 256);
        uint4 v1 = *reinterpret_cast<const uint4*>(hp + (size_t)bucket[e + 2] * 256);
        acc8(v0, s); acc8(v1, s);
    }
    if (e < end)
        acc8(*reinterpret_cast<const uint4*>(hp + (size_t)bucket[e] * 256), s);
    #pragma unroll
    for (int j = 0; j < 8; ++j) s[j] += __shfl_xor(s[j], 32);
    if (g == 0) {
        int d = end - beg;
        float sc = 1.0f / (float)(d > 1 ? d : 1);
        uint4 o;
        o.x = (unsigned)f2b(s[0]*sc) | ((unsigned)f2b(s[1]*sc) << 16);
        o.y = (unsigned)f2b(s[2]*sc) | ((unsigned)f2b(s[3]*sc) << 16);
        o.z = (unsigned)f2b(s[4]*sc) | ((unsigned)f2b(s[5]*sc) << 16);
        o.w = (unsigned)f2b(s[6]*sc) | ((unsigned)f2b(s[7]*sc) << 16);
        *reinterpret_cast<uint4*>(agg + (size_t)node * 256 + c * 8) = o;
    }
}

// ---------------- conv GEMM: H = relu(bias + Aagg@Wl^T + Aself@Wr^T), bf16 out ----------------

__global__ __launch_bounds__(256) void k_conv_gemm(const unsigned short* __restrict__ Aagg,
                                                   const unsigned short* __restrict__ Aself,
                                                   const unsigned short* __restrict__ Wck,
                                                   const float* __restrict__ bias,
                                                   unsigned short* __restrict__ Hout,
                                                   int Nn, int F) {
    __shared__ __align__(16) unsigned short zt[128 * 32];
    __shared__ __align__(16) unsigned short wt[128 * 32];
    const int t = threadIdx.x;
    const int lane = t & 63, w = t >> 6;
    const int wm = w >> 1, wn = w & 1;
    const int node0 = blockIdx.x * 128;
    const int colh = blockIdx.y;
    const int half = F >> 5, nchunks = F >> 4;

    f32x4 acc[4][4];
    #pragma unroll
    for (int i = 0; i < 4; ++i)
        #pragma unroll
        for (int j = 0; j < 4; ++j) acc[i][j] = (f32x4){0.f, 0.f, 0.f, 0.f};

    for (int c = 0; c < nchunks; ++c) {
        __syncthreads();
        const unsigned short* Asrc = (c < half) ? Aagg : Aself;
        const int ccol = ((c < half) ? c : c - half) * 32;
        #pragma unroll
        for (int p = 0; p < 2; ++p) {
            int fc = t + p * 256;
            int row = fc >> 2, seg = fc & 3;
            int node = node0 + row; if (node >= Nn) node = Nn - 1;
            uint4 v = *reinterpret_cast<const uint4*>(Asrc + (size_t)node * F + ccol + seg * 8);
            *reinterpret_cast<uint4*>(&zt[row * 32 + swz(row, seg) * 8]) = v;
        }
        const unsigned short* Wsrc = Wck + ((size_t)c * 256 + colh * 128) * 32;
        #pragma unroll
        for (int p = 0; p < 2; ++p) {
            int fc = t + p * 256;
            int row = fc >> 2, seg = fc & 3;
            *reinterpret_cast<uint4*>(&wt[row * 32 + swz(row, seg) * 8]) =
                *reinterpret_cast<const uint4*>(Wsrc + fc * 8);
        }
        __syncthreads();
        bf16x8 a[4], b[4];
        const int q = lane >> 4;
        #pragma unroll
        for (int mi = 0; mi < 4; ++mi) {
            int R = wm * 64 + mi * 16 + (lane & 15);
            a[mi] = *reinterpret_cast<const bf16x8*>(&zt[R * 32 + swz(R, q) * 8]);
        }
        #pragma unroll
        for (int ni = 0; ni < 4; ++ni) {
            int R = wn * 64 + ni * 16 + (lane & 15);
            b[ni] = *reinterpret_cast<const bf16x8*>(&wt[R * 32 + swz(R, q) * 8]);
        }
        #pragma unroll
        for (int mi = 0; mi < 4; ++mi)
            #pragma unroll
            for (int ni = 0; ni < 4; ++ni)
                acc[mi][ni] = __builtin_amdgcn_mfma_f32_16x16x32_bf16(a[mi], b[ni], acc[mi][ni], 0, 0, 0);
    }

    #pragma unroll
    for (int mi = 0; mi < 4; ++mi)
        #pragma unroll
        for (int ni = 0; ni < 4; ++ni) {
            int col = colh * 128 + wn * 64 + ni * 16 + (lane & 15);
            float bia = bias[col];
            #pragma unroll
            for (int r = 0; r < 4; ++r) {
                int row = node0 + wm * 64 + mi * 16 + ((lane >> 4) << 2) + r;
                if (row < Nn) {
                    float v = acc[mi][ni][r] + bia;
                    v = v > 0.f ? v : 0.f;
                    Hout[(size_t)row * 256 + col] = f2b(v);
                }
            }
        }
}

// ---------------- G GEMM: G2 = h2 @ [W1u;W1v]^T  ([N][512] bf16, no bias/relu) ----------------

__global__ __launch_bounds__(256) void k_gemm_g(const unsigned short* __restrict__ A,
                                                const unsigned short* __restrict__ Wck,
                                                unsigned short* __restrict__ Gout,
                                                int Nn) {
    __shared__ __align__(16) unsigned short zt[128 * 32];
    __shared__ __align__(16) unsigned short wt[128 * 32];
    const int t = threadIdx.x;
    const int lane = t & 63, w = t >> 6;
    const int wm = w >> 1, wn = w & 1;
    const int node0 = blockIdx.x * 128;
    const int colg = blockIdx.y;          // 0..3 -> 128-col group of 512

    f32x4 acc[4][4];
    #pragma unroll
    for (int i = 0; i < 4; ++i)
        #pragma unroll
        for (int j = 0; j < 4; ++j) acc[i][j] = (f32x4){0.f, 0.f, 0.f, 0.f};

    for (int c = 0; c < 8; ++c) {
        __syncthreads();
        #pragma unroll
        for (int p = 0; p < 2; ++p) {
            int fc = t + p * 256;
            int row = fc >> 2, seg = fc & 3;
            int node = node0 + row; if (node >= Nn) node = Nn - 1;
            uint4 v = *reinterpret_cast<const uint4*>(A + (size_t)node * 256 + c * 32 + seg * 8);
            *reinterpret_cast<uint4*>(&zt[row * 32 + swz(row, seg) * 8]) = v;
        }
        const unsigned short* Wsrc = Wck + ((size_t)c * 512 + colg * 128) * 32;
        #pragma unroll
        for (int p = 0; p < 2; ++p) {
            int fc = t + p * 256;
            int row = fc >> 2, seg = fc & 3;
            *reinterpret_cast<uint4*>(&wt[row * 32 + swz(row, seg) * 8]) =
                *reinterpret_cast<const uint4*>(Wsrc + fc * 8);
        }
        __syncthreads();
        bf16x8 a[4], b[4];
        const int q = lane >> 4;
        #pragma unroll
        for (int mi = 0; mi < 4; ++mi) {
            int R = wm * 64 + mi * 16 + (lane & 15);
            a[mi] = *reinterpret_cast<const bf16x8*>(&zt[R * 32 + swz(R, q) * 8]);
        }
        #pragma unroll
        for (int ni = 0; ni < 4; ++ni) {
            int R = wn * 64 + ni * 16 + (lane & 15);
            b[ni] = *reinterpret_cast<const bf16x8*>(&wt[R * 32 + swz(R, q) * 8]);
        }
        #pragma unroll
        for (int mi = 0; mi < 4; ++mi)
            #pragma unroll
            for (int ni = 0; ni < 4; ++ni)
                acc[mi][ni] = __builtin_amdgcn_mfma_f32_16x16x32_bf16(a[mi], b[ni], acc[mi][ni], 0, 0, 0);
    }

    #pragma unroll
    for (int mi = 0; mi < 4; ++mi)
        #pragma unroll
        for (int ni = 0; ni < 4; ++ni) {
            int col = colg * 128 + wn * 64 + ni * 16 + (lane & 15);
            #pragma unroll
            for (int r = 0; r < 4; ++r) {
                int row = node0 + wm * 64 + mi * 16 + ((lane >> 4) << 2) + r;
                if (row < Nn)
                    Gout[(size_t)row * 512 + col] = f2b(acc[mi][ni][r]);
            }
        }
}

// ---------------- edge kernel ----------------
// out[e] = logexp[e] + b2 + sum_j relu(Gu[u][j] + Gv[v][j] + acc_j) * W2[j]
// acc = MFMA(W1a_pad frags, attr_pad^T frags); 16 edges per wave, 64 per block.

__global__ __launch_bounds__(256) void k_edge(const unsigned short* __restrict__ G2,
                                              const float* __restrict__ attr,
                                              const int* __restrict__ eu,
                                              const int* __restrict__ ev,
                                              const uint4* __restrict__ WaF,
                                              const float* __restrict__ W2,
                                              const float* __restrict__ b2,
                                              const float* __restrict__ logexp,
                                              float* __restrict__ out, int P) {
    __shared__ __align__(16) unsigned short attrT[64 * 32];
    const int t = threadIdx.x;
    const int lane = t & 63, w = t >> 6;
    const int base = blockIdx.x * 64;

    // stage attr -> attrT bf16 (cols 0..15 attr, col 16 = 1.0 (b1 row), 17..31 = 0)
    {
        int e = t >> 2, seg = t & 3;
        int eg = base + e; if (eg >= P) eg = P - 1;
        const float4 f = *reinterpret_cast<const float4*>(attr + (size_t)eg * 16 + seg * 4);
        uint2 o;
        o.x = (unsigned)f2b(f.x) | ((unsigned)f2b(f.y) << 16);
        o.y = (unsigned)f2b(f.z) | ((unsigned)f2b(f.w) << 16);
        *reinterpret_cast<uint2*>(&attrT[e * 32 + seg * 4]) = o;
    }
    if (t < 64) {
        uint2 z0; z0.x = 0x3f80u; z0.y = 0u;                   // cols 16,17 = 1.0,0 ; 18,19 = 0
        *reinterpret_cast<uint2*>(&attrT[t * 32 + 16]) = z0;
        uint2 z1; z1.x = 0u; z1.y = 0u;
        *reinterpret_cast<uint2*>(&attrT[t * 32 + 20]) = z1;
        uint4 z2; z2.x = z2.y = z2.z = z2.w = 0u;
        *reinterpret_cast<uint4*>(&attrT[t * 32 + 24]) = z2;
    }
    __syncthreads();

    const int el = lane & 15, q = lane >> 4;
    // B-fragment: attr_pad^T for this wave's 16 edges
    const bf16x8 bfrag = *reinterpret_cast<const bf16x8*>(&attrT[(w * 16 + el) * 32 + q * 8]);

    int eg = base + w * 16 + el;
    bool valid = eg < P;
    if (!valid) eg = P - 1;
    const int u = eu[eg], v = ev[eg];
    const unsigned short* gu = G2 + (size_t)u * 512 + q * 4;
    const unsigned short* gv = G2 + (size_t)v * 512 + 256 + q * 4;

    float s = 0.f;
    #pragma unroll
    for (int mi = 0; mi < 16; ++mi) {
        const bf16x8 af = *reinterpret_cast<const bf16x8*>(&WaF[mi * 64 + lane]);
        f32x4 acc = __builtin_amdgcn_mfma_f32_16x16x32_bf16(af, bfrag, (f32x4){0.f,0.f,0.f,0.f}, 0, 0, 0);
        const uint2 guv = *reinterpret_cast<const uint2*>(gu + mi * 16);
        const uint2 gvv = *reinterpret_cast<const uint2*>(gv + mi * 16);
        const float4 w2v = *reinterpret_cast<const float4*>(W2 + mi * 16 + q * 4);
        float y0 = acc[0] + b2f((unsigned short)(guv.x & 0xffffu)) + b2f((unsigned short)(gvv.x & 0xffffu));
        float y1 = acc[1] + b2f((unsigned short)(guv.x >> 16))     + b2f((unsigned short)(gvv.x >> 16));
        float y2 = acc[2] + b2f((unsigned short)(guv.y & 0xffffu)) + b2f((unsigned short)(gvv.y & 0xffffu));
        float y3 = acc[3] + b2f((unsigned short)(guv.y >> 16))     + b2f((unsigned short)(gvv.y >> 16));
        s += (y0 > 0.f ? y0 : 0.f) * w2v.x;
        s += (y1 > 0.f ? y1 : 0.f) * w2v.y;
        s += (y2 > 0.f ? y2 : 0.f) * w2v.z;
        s += (y3 > 0.f ? y3 : 0.f) * w2v.w;
    }
    s += __shfl_xor(s, 16);
    s += __shfl_xor(s, 32);
    if (q == 0 && valid)
        out[eg] = logexp[eg] + b2[0] + s;
}

// ---------------- launch ----------------

extern "C" void kernel_launch(void* const* d_in, const int* in_sizes, int n_in,
                              void* d_out, int out_size, void* d_ws, size_t ws_size,
                              hipStream_t stream) {
    const float* x      = (const float*)d_in[0];
    const int*   eidx   = (const int*)d_in[1];
    const int*   eu     = (const int*)d_in[2];
    const int*   ev     = (const int*)d_in[3];
    const float* attr   = (const float*)d_in[4];
    const float* logexp = (const float*)d_in[5];
    const float* Wl1    = (const float*)d_in[6];
    const float* bl1    = (const float*)d_in[7];
    const float* Wr1    = (const float*)d_in[8];
    const float* Wl2    = (const float*)d_in[9];
    const float* bl2    = (const float*)d_in[10];
    const float* Wr2    = (const float*)d_in[11];
    const float* W1     = (const float*)d_in[12];
    const float* b1     = (const float*)d_in[13];
    const float* W2     = (const float*)d_in[14];
    const float* b2     = (const float*)d_in[15];
    float* out = (float*)d_out;

    const int N = in_sizes[0] / 128;
    const int E = in_sizes[1] / 2;
    const int P = in_sizes[2];
    const int* src = eidx;
    const int* dst = eidx + E;

    char* ws = (char*)d_ws;
    size_t off = 0;
    auto alloc = [&](size_t bytes) -> void* {
        off = (off + 255) & ~(size_t)255;
        void* p = ws + off;
        off += bytes;
        return p;
    };
    int* row_ptr = (int*)alloc((size_t)(N + 1) * 4);
    int* cursor  = (int*)alloc((size_t)N * 4);
    int* bucket  = (int*)alloc((size_t)E * 4);
    unsigned short* h1 = (unsigned short*)alloc((size_t)N * 256 * 2);
    unsigned short* h2 = (unsigned short*)alloc((size_t)N * 256 * 2);
    // shared region: {xb, agg1, agg2} overlaid later by G2 [N][512]
    char* shared_base = (char*)alloc((size_t)N * 512 * 2);
    unsigned short* xb   = (unsigned short*)shared_base;                         // N*128
    unsigned short* agg1 = (unsigned short*)(shared_base + (size_t)N * 128 * 2); // N*128
    unsigned short* agg2 = (unsigned short*)(shared_base + (size_t)N * 256 * 2); // N*256
    unsigned short* G2   = (unsigned short*)shared_base;                         // N*512
    unsigned short* Wc1  = (unsigned short*)alloc((size_t)65536 * 2);
    unsigned short* Wc2  = (unsigned short*)alloc((size_t)131072 * 2);
    unsigned short* W1g  = (unsigned short*)alloc((size_t)131072 * 2);
    unsigned short* WaF  = (unsigned short*)alloc((size_t)8192 * 2);

    hipMemsetAsync(cursor, 0, (size_t)N * 4, stream);
    k_count<<<(E + 255) / 256, 256, 0, stream>>>(dst, cursor, E);
    k_scan<<<1, 1024, 0, stream>>>(cursor, row_ptr, N);
    k_scatter<<<(E + 255) / 256, 256, 0, stream>>>(src, dst, cursor, bucket, E);
    k_convert_weights<<<(65536 + 131072 + 131072 + 8192 + 255) / 256, 256, 0, stream>>>(
        Wl1, Wr1, Wl2, Wr2, W1, b1, Wc1, Wc2, W1g, WaF);
    k_f2b_copy<<<(N * 128 + 255) / 256, 256, 0, stream>>>(x, xb, N * 128);

    k_agg_x<<<(N + 3) / 4, 256, 0, stream>>>(xb, row_ptr, bucket, agg1, N);
    dim3 gconv((N + 127) / 128, 2);
    k_conv_gemm<<<gconv, 256, 0, stream>>>(agg1, xb, Wc1, bl1, h1, N, 128);
    k_agg_h<<<(N + 3) / 4, 256, 0, stream>>>(h1, row_ptr, bucket, agg2, N);
    k_conv_gemm<<<gconv, 256, 0, stream>>>(agg2, h1, Wc2, bl2, h2, N, 256);

    dim3 gg((N + 127) / 128, 4);
    k_gemm_g<<<gg, 256, 0, stream>>>(h2, W1g, G2, N);
    k_edge<<<(P + 63) / 64, 256, 0, stream>>>(G2, attr, eu, ev, (const uint4*)WaF,
                                              W2, b2, logexp, out, P);
}

// Round 5
// 525.532 us; speedup vs baseline: 1.6830x; 1.1422x over previous
//
#include <hip/hip_runtime.h>

// GraphSAGE_13993003450942 — round 5 = round 4 with the k_edge phase-B fix:
// gt row index must be block-local edge (w*16+el), not el.

typedef float f32x4 __attribute__((ext_vector_type(4)));
typedef __bf16 bf16x8 __attribute__((ext_vector_type(8)));

__device__ __forceinline__ unsigned short f2b(float f) {
    unsigned u = __float_as_uint(f);
    u = u + 0x7fffu + ((u >> 16) & 1u);   // RNE
    return (unsigned short)(u >> 16);
}
__device__ __forceinline__ float b2f(unsigned short s) {
    return __uint_as_float(((unsigned)s) << 16);
}
__device__ __forceinline__ float blo(unsigned x) { return b2f((unsigned short)(x & 0xffffu)); }
__device__ __forceinline__ float bhi(unsigned x) { return b2f((unsigned short)(x >> 16)); }
__device__ __forceinline__ unsigned packsum(unsigned a, unsigned b) {
    return (unsigned)f2b(blo(a) + blo(b)) | ((unsigned)f2b(bhi(a) + bhi(b)) << 16);
}
__device__ __forceinline__ int swz(int r, int g) { return (g + (r >> 1)) & 3; }

// ---------------- CSR build ----------------

__global__ void k_count(const int* __restrict__ dst, int* __restrict__ cnt, int E) {
    int e = blockIdx.x * 256 + threadIdx.x;
    if (e < E) atomicAdd(&cnt[dst[e]], 1);
}

__global__ __launch_bounds__(1024) void k_scan(int* __restrict__ cnt_cursor,
                                               int* __restrict__ row_ptr, int n) {
    __shared__ int wsum[16];
    __shared__ int carry;
    int t = threadIdx.x, lane = t & 63, w = t >> 6;
    if (t == 0) carry = 0;
    __syncthreads();
    int nch = (n + 1023) >> 10;
    for (int ch = 0; ch < nch; ++ch) {
        int i = (ch << 10) + t;
        int v = (i < n) ? cnt_cursor[i] : 0;
        int s = v;
        #pragma unroll
        for (int off = 1; off < 64; off <<= 1) {
            int u = __shfl_up(s, off);
            if (lane >= off) s += u;
        }
        if (lane == 63) wsum[w] = s;
        __syncthreads();
        int wpre = 0;
        for (int j = 0; j < w; ++j) wpre += wsum[j];
        int incl = s + wpre;
        int base = carry;
        if (i < n) { int ex = base + incl - v; row_ptr[i] = ex; cnt_cursor[i] = ex; }
        __syncthreads();
        if (t == 1023) carry = base + incl;
    }
    __syncthreads();
    if (t == 0) row_ptr[n] = carry;
}

__global__ void k_scatter(const int* __restrict__ src, const int* __restrict__ dst,
                          int* __restrict__ cursor, int* __restrict__ bucket, int E) {
    int e = blockIdx.x * 256 + threadIdx.x;
    if (e < E) {
        int p = atomicAdd(&cursor[dst[e]], 1);
        bucket[p] = src[e];
    }
}

// ---------------- conversions / weight repack ----------------
// Wc1 [8][256][32] (Wl1|Wr1), Wc2 [16][256][32] (Wl2|Wr2),
// W1g [8][512][32] (rows 0-255: W1[:,0:256]; rows 256-511: W1[:,256:512]),
// WaF [16][64][8] bf16 A-fragments of W1a_pad (k<16: W1[:,512+k]; k==16: b1; else 0)

__global__ void k_convert_weights(const float* __restrict__ Wl1, const float* __restrict__ Wr1,
                                  const float* __restrict__ Wl2, const float* __restrict__ Wr2,
                                  const float* __restrict__ W1, const float* __restrict__ b1,
                                  unsigned short* __restrict__ Wc1,
                                  unsigned short* __restrict__ Wc2,
                                  unsigned short* __restrict__ W1g,
                                  unsigned short* __restrict__ WaF) {
    int idx = blockIdx.x * 256 + threadIdx.x;
    if (idx < 65536) {
        int c = idx >> 13, j = (idx >> 5) & 255, kk = idx & 31;
        float v = (c < 4) ? Wl1[j * 128 + c * 32 + kk] : Wr1[j * 128 + (c - 4) * 32 + kk];
        Wc1[idx] = f2b(v);
    } else if (idx < 65536 + 131072) {
        int i2 = idx - 65536;
        int c = i2 >> 13, j = (i2 >> 5) & 255, kk = i2 & 31;
        float v = (c < 8) ? Wl2[j * 256 + c * 32 + kk] : Wr2[j * 256 + (c - 8) * 32 + kk];
        Wc2[i2] = f2b(v);
    } else if (idx < 65536 + 131072 + 131072) {
        int i3 = idx - 65536 - 131072;
        int c = i3 >> 14, j = (i3 >> 5) & 511, kk = i3 & 31;
        float v = (j < 256) ? W1[(size_t)j * 528 + c * 32 + kk]
                            : W1[(size_t)(j - 256) * 528 + 256 + c * 32 + kk];
        W1g[i3] = f2b(v);
    } else if (idx < 65536 + 131072 + 131072 + 8192) {
        int i4 = idx - 65536 - 131072 - 131072;
        int mi = i4 >> 9, l = (i4 >> 3) & 63, j = i4 & 7;
        int m = mi * 16 + (l & 15);
        int k = (l >> 4) * 8 + j;
        float v = (k < 16) ? W1[(size_t)m * 528 + 512 + k] : (k == 16 ? b1[m] : 0.f);
        WaF[i4] = f2b(v);
    }
}

__global__ void k_f2b_copy(const float* __restrict__ in, unsigned short* __restrict__ out, int n) {
    int i = blockIdx.x * 256 + threadIdx.x;
    if (i < n) out[i] = f2b(in[i]);
}

// ---------------- aggregation (mean over in-neighbors) ----------------

__device__ __forceinline__ void acc8(uint4 v, float* s) {
    s[0] += blo(v.x); s[1] += bhi(v.x);
    s[2] += blo(v.y); s[3] += bhi(v.y);
    s[4] += blo(v.z); s[5] += bhi(v.z);
    s[6] += blo(v.w); s[7] += bhi(v.w);
}

// xb bf16 [N][128]; 4 subgroups x 16 lanes x 16B; contiguous quarter-ranges, unroll-4
__global__ __launch_bounds__(256) void k_agg_x(const unsigned short* __restrict__ xb,
                                               const int* __restrict__ row_ptr,
                                               const int* __restrict__ bucket,
                                               unsigned short* __restrict__ agg, int Nn) {
    int node = blockIdx.x * 4 + (threadIdx.x >> 6);
    if (node >= Nn) return;
    int lane = threadIdx.x & 63;
    int q = lane >> 4, c = lane & 15;
    int beg = row_ptr[node], end = row_ptr[node + 1];
    int len = end - beg;
    int lo = beg + ((len * q) >> 2);
    int hi = beg + ((len * (q + 1)) >> 2);
    float s[8] = {0.f,0.f,0.f,0.f,0.f,0.f,0.f,0.f};
    const unsigned short* xp = xb + c * 8;
    int e = lo;
    for (; e + 4 <= hi; e += 4) {
        int b0 = bucket[e], b1 = bucket[e + 1], b2 = bucket[e + 2], b3 = bucket[e + 3];
        uint4 v0 = *reinterpret_cast<const uint4*>(xp + (size_t)b0 * 128);
        uint4 v1 = *reinterpret_cast<const uint4*>(xp + (size_t)b1 * 128);
        uint4 v2 = *reinterpret_cast<const uint4*>(xp + (size_t)b2 * 128);
        uint4 v3 = *reinterpret_cast<const uint4*>(xp + (size_t)b3 * 128);
        acc8(v0, s); acc8(v1, s); acc8(v2, s); acc8(v3, s);
    }
    for (; e < hi; ++e)
        acc8(*reinterpret_cast<const uint4*>(xp + (size_t)bucket[e] * 128), s);
    #pragma unroll
    for (int j = 0; j < 8; ++j) {
        s[j] += __shfl_xor(s[j], 16);
        s[j] += __shfl_xor(s[j], 32);
    }
    if (q == 0) {
        float sc = 1.0f / (float)(len > 1 ? len : 1);
        uint4 o;
        o.x = (unsigned)f2b(s[0]*sc) | ((unsigned)f2b(s[1]*sc) << 16);
        o.y = (unsigned)f2b(s[2]*sc) | ((unsigned)f2b(s[3]*sc) << 16);
        o.z = (unsigned)f2b(s[4]*sc) | ((unsigned)f2b(s[5]*sc) << 16);
        o.w = (unsigned)f2b(s[6]*sc) | ((unsigned)f2b(s[7]*sc) << 16);
        *reinterpret_cast<uint4*>(agg + (size_t)node * 128 + c * 8) = o;
    }
}

// h bf16 [N][256]; 2 subgroups x 32 lanes x 16B; contiguous half-ranges, unroll-4
__global__ __launch_bounds__(256) void k_agg_h(const unsigned short* __restrict__ h,
                                               const int* __restrict__ row_ptr,
                                               const int* __restrict__ bucket,
                                               unsigned short* __restrict__ agg, int Nn) {
    int node = blockIdx.x * 4 + (threadIdx.x >> 6);
    if (node >= Nn) return;
    int lane = threadIdx.x & 63;
    int g = lane >> 5, c = lane & 31;
    int beg = row_ptr[node], end = row_ptr[node + 1];
    int len = end - beg;
    int lo = beg + ((len * g) >> 1);
    int hi = beg + ((len * (g + 1)) >> 1);
    float s[8] = {0.f,0.f,0.f,0.f,0.f,0.f,0.f,0.f};
    const unsigned short* hp = h + c * 8;
    int e = lo;
    for (; e + 4 <= hi; e += 4) {
        int b0 = bucket[e], b1 = bucket[e + 1], b2 = bucket[e + 2], b3 = bucket[e + 3];
        uint4 v0 = *reinterpret_cast<const uint4*>(hp + (size_t)b0 * 256);
        uint4 v1 = *reinterpret_cast<const uint4*>(hp + (size_t)b1 * 256);
        uint4 v2 = *reinterpret_cast<const uint4*>(hp + (size_t)b2 * 256);
        uint4 v3 = *reinterpret_cast<const uint4*>(hp + (size_t)b3 * 256);
        acc8(v0, s); acc8(v1, s); acc8(v2, s); acc8(v3, s);
    }
    for (; e < hi; ++e)
        acc8(*reinterpret_cast<const uint4*>(hp + (size_t)bucket[e] * 256), s);
    #pragma unroll
    for (int j = 0; j < 8; ++j) s[j] += __shfl_xor(s[j], 32);
    if (g == 0) {
        float sc = 1.0f / (float)(len > 1 ? len : 1);
        uint4 o;
        o.x = (unsigned)f2b(s[0]*sc) | ((unsigned)f2b(s[1]*sc) << 16);
        o.y = (unsigned)f2b(s[2]*sc) | ((unsigned)f2b(s[3]*sc) << 16);
        o.z = (unsigned)f2b(s[4]*sc) | ((unsigned)f2b(s[5]*sc) << 16);
        o.w = (unsigned)f2b(s[6]*sc) | ((unsigned)f2b(s[7]*sc) << 16);
        *reinterpret_cast<uint4*>(agg + (size_t)node * 256 + c * 8) = o;
    }
}

// ---------------- conv GEMM: H = relu(bias + Aagg@Wl^T + Aself@Wr^T), bf16 out ----------------

__global__ __launch_bounds__(256) void k_conv_gemm(const unsigned short* __restrict__ Aagg,
                                                   const unsigned short* __restrict__ Aself,
                                                   const unsigned short* __restrict__ Wck,
                                                   const float* __restrict__ bias,
                                                   unsigned short* __restrict__ Hout,
                                                   int Nn, int F) {
    __shared__ __align__(16) unsigned short zt[128 * 32];
    __shared__ __align__(16) unsigned short wt[128 * 32];
    const int t = threadIdx.x;
    const int lane = t & 63, w = t >> 6;
    const int wm = w >> 1, wn = w & 1;
    const int node0 = blockIdx.x * 128;
    const int colh = blockIdx.y;
    const int half = F >> 5, nchunks = F >> 4;

    f32x4 acc[4][4];
    #pragma unroll
    for (int i = 0; i < 4; ++i)
        #pragma unroll
        for (int j = 0; j < 4; ++j) acc[i][j] = (f32x4){0.f, 0.f, 0.f, 0.f};

    for (int c = 0; c < nchunks; ++c) {
        __syncthreads();
        const unsigned short* Asrc = (c < half) ? Aagg : Aself;
        const int ccol = ((c < half) ? c : c - half) * 32;
        #pragma unroll
        for (int p = 0; p < 2; ++p) {
            int fc = t + p * 256;
            int row = fc >> 2, seg = fc & 3;
            int node = node0 + row; if (node >= Nn) node = Nn - 1;
            uint4 v = *reinterpret_cast<const uint4*>(Asrc + (size_t)node * F + ccol + seg * 8);
            *reinterpret_cast<uint4*>(&zt[row * 32 + swz(row, seg) * 8]) = v;
        }
        const unsigned short* Wsrc = Wck + ((size_t)c * 256 + colh * 128) * 32;
        #pragma unroll
        for (int p = 0; p < 2; ++p) {
            int fc = t + p * 256;
            int row = fc >> 2, seg = fc & 3;
            *reinterpret_cast<uint4*>(&wt[row * 32 + swz(row, seg) * 8]) =
                *reinterpret_cast<const uint4*>(Wsrc + fc * 8);
        }
        __syncthreads();
        bf16x8 a[4], b[4];
        const int q = lane >> 4;
        #pragma unroll
        for (int mi = 0; mi < 4; ++mi) {
            int R = wm * 64 + mi * 16 + (lane & 15);
            a[mi] = *reinterpret_cast<const bf16x8*>(&zt[R * 32 + swz(R, q) * 8]);
        }
        #pragma unroll
        for (int ni = 0; ni < 4; ++ni) {
            int R = wn * 64 + ni * 16 + (lane & 15);
            b[ni] = *reinterpret_cast<const bf16x8*>(&wt[R * 32 + swz(R, q) * 8]);
        }
        #pragma unroll
        for (int mi = 0; mi < 4; ++mi)
            #pragma unroll
            for (int ni = 0; ni < 4; ++ni)
                acc[mi][ni] = __builtin_amdgcn_mfma_f32_16x16x32_bf16(a[mi], b[ni], acc[mi][ni], 0, 0, 0);
    }

    #pragma unroll
    for (int mi = 0; mi < 4; ++mi)
        #pragma unroll
        for (int ni = 0; ni < 4; ++ni) {
            int col = colh * 128 + wn * 64 + ni * 16 + (lane & 15);
            float bia = bias[col];
            #pragma unroll
            for (int r = 0; r < 4; ++r) {
                int row = node0 + wm * 64 + mi * 16 + ((lane >> 4) << 2) + r;
                if (row < Nn) {
                    float v = acc[mi][ni][r] + bia;
                    v = v > 0.f ? v : 0.f;
                    Hout[(size_t)row * 256 + col] = f2b(v);
                }
            }
        }
}

// ---------------- G GEMM: G2 = h2 @ [W1u;W1v]^T  ([N][512] bf16) ----------------

__global__ __launch_bounds__(256) void k_gemm_g(const unsigned short* __restrict__ A,
                                                const unsigned short* __restrict__ Wck,
                                                unsigned short* __restrict__ Gout,
                                                int Nn) {
    __shared__ __align__(16) unsigned short zt[128 * 32];
    __shared__ __align__(16) unsigned short wt[128 * 32];
    const int t = threadIdx.x;
    const int lane = t & 63, w = t >> 6;
    const int wm = w >> 1, wn = w & 1;
    const int node0 = blockIdx.x * 128;
    const int colg = blockIdx.y;

    f32x4 acc[4][4];
    #pragma unroll
    for (int i = 0; i < 4; ++i)
        #pragma unroll
        for (int j = 0; j < 4; ++j) acc[i][j] = (f32x4){0.f, 0.f, 0.f, 0.f};

    for (int c = 0; c < 8; ++c) {
        __syncthreads();
        #pragma unroll
        for (int p = 0; p < 2; ++p) {
            int fc = t + p * 256;
            int row = fc >> 2, seg = fc & 3;
            int node = node0 + row; if (node >= Nn) node = Nn - 1;
            uint4 v = *reinterpret_cast<const uint4*>(A + (size_t)node * 256 + c * 32 + seg * 8);
            *reinterpret_cast<uint4*>(&zt[row * 32 + swz(row, seg) * 8]) = v;
        }
        const unsigned short* Wsrc = Wck + ((size_t)c * 512 + colg * 128) * 32;
        #pragma unroll
        for (int p = 0; p < 2; ++p) {
            int fc = t + p * 256;
            int row = fc >> 2, seg = fc & 3;
            *reinterpret_cast<uint4*>(&wt[row * 32 + swz(row, seg) * 8]) =
                *reinterpret_cast<const uint4*>(Wsrc + fc * 8);
        }
        __syncthreads();
        bf16x8 a[4], b[4];
        const int q = lane >> 4;
        #pragma unroll
        for (int mi = 0; mi < 4; ++mi) {
            int R = wm * 64 + mi * 16 + (lane & 15);
            a[mi] = *reinterpret_cast<const bf16x8*>(&zt[R * 32 + swz(R, q) * 8]);
        }
        #pragma unroll
        for (int ni = 0; ni < 4; ++ni) {
            int R = wn * 64 + ni * 16 + (lane & 15);
            b[ni] = *reinterpret_cast<const bf16x8*>(&wt[R * 32 + swz(R, q) * 8]);
        }
        #pragma unroll
        for (int mi = 0; mi < 4; ++mi)
            #pragma unroll
            for (int ni = 0; ni < 4; ++ni)
                acc[mi][ni] = __builtin_amdgcn_mfma_f32_16x16x32_bf16(a[mi], b[ni], acc[mi][ni], 0, 0, 0);
    }

    #pragma unroll
    for (int mi = 0; mi < 4; ++mi)
        #pragma unroll
        for (int ni = 0; ni < 4; ++ni) {
            int col = colg * 128 + wn * 64 + ni * 16 + (lane & 15);
            #pragma unroll
            for (int r = 0; r < 4; ++r) {
                int row = node0 + wm * 64 + mi * 16 + ((lane >> 4) << 2) + r;
                if (row < Nn)
                    Gout[(size_t)row * 512 + col] = f2b(acc[mi][ni][r]);
            }
        }
}

// ---------------- edge kernel v2 (fixed) ----------------
// Phase A: per wave, gather 16 edges (2/instr contiguous): g = Gu[u]+Gv[v] -> LDS bf16.
// Phase B: MFMA attr-term (W1a_pad, b1 folded) + g + relu·W2 reduce in C-layout.
// Each wave reads only the gt rows it wrote (w*16+el) — no inter-wave barrier needed.

__global__ __launch_bounds__(256) void k_edge(const unsigned short* __restrict__ G2,
                                              const float* __restrict__ attr,
                                              const int* __restrict__ eu,
                                              const int* __restrict__ ev,
                                              const uint4* __restrict__ WaF,
                                              const float* __restrict__ W2,
                                              const float* __restrict__ b2,
                                              const float* __restrict__ logexp,
                                              float* __restrict__ out, int P) {
    __shared__ __align__(16) unsigned short attrT[64 * 40];   // stride 40: bank-spread
    __shared__ __align__(16) unsigned short gt[64 * 264];     // stride 264: 2-way max
    __shared__ float w2s[256];
    const int t = threadIdx.x;
    const int lane = t & 63, w = t >> 6;
    const int base = blockIdx.x * 64;

    // stage attr -> attrT (cols 0..15 attr, 16 = 1.0 (b1 row), 17..31 = 0)
    {
        int e = t >> 2, seg = t & 3;
        int eg = base + e; if (eg >= P) eg = P - 1;
        const float4 f = *reinterpret_cast<const float4*>(attr + (size_t)eg * 16 + seg * 4);
        uint2 o;
        o.x = (unsigned)f2b(f.x) | ((unsigned)f2b(f.y) << 16);
        o.y = (unsigned)f2b(f.z) | ((unsigned)f2b(f.w) << 16);
        *reinterpret_cast<uint2*>(&attrT[e * 40 + seg * 4]) = o;
    }
    if (t < 64) {
        uint2 z0; z0.x = 0x3f80u; z0.y = 0u;
        *reinterpret_cast<uint2*>(&attrT[t * 40 + 16]) = z0;
        uint2 z1; z1.x = 0u; z1.y = 0u;
        *reinterpret_cast<uint2*>(&attrT[t * 40 + 20]) = z1;
        uint4 z2; z2.x = z2.y = z2.z = z2.w = 0u;
        *reinterpret_cast<uint4*>(&attrT[t * 40 + 24]) = z2;
    }
    w2s[t] = W2[t];
    __syncthreads();

    // phase A: contiguous gather, 2 edges per instruction
    {
        const int h = lane >> 5, c = lane & 31;
        #pragma unroll
        for (int i = 0; i < 8; ++i) {
            int el = w * 16 + 2 * i + h;
            int eg = base + el; if (eg >= P) eg = P - 1;
            int u = eu[eg], v = ev[eg];
            uint4 a = *reinterpret_cast<const uint4*>(G2 + (size_t)u * 512 + c * 8);
            uint4 bb = *reinterpret_cast<const uint4*>(G2 + (size_t)v * 512 + 256 + c * 8);
            uint4 o;
            o.x = packsum(a.x, bb.x);
            o.y = packsum(a.y, bb.y);
            o.z = packsum(a.z, bb.z);
            o.w = packsum(a.w, bb.w);
            *reinterpret_cast<uint4*>(&gt[el * 264 + c * 8]) = o;
        }
    }

    // phase B: attr-term MFMA + combine
    const int el = lane & 15, q = lane >> 4;
    const int grow = w * 16 + el;          // block-local edge row in gt (THE FIX)
    const bf16x8 bfrag = *reinterpret_cast<const bf16x8*>(&attrT[grow * 40 + q * 8]);
    float s = 0.f;
    #pragma unroll
    for (int mi = 0; mi < 16; ++mi) {
        const bf16x8 af = *reinterpret_cast<const bf16x8*>(&WaF[mi * 64 + lane]);
        f32x4 acc = __builtin_amdgcn_mfma_f32_16x16x32_bf16(af, bfrag, (f32x4){0.f,0.f,0.f,0.f}, 0, 0, 0);
        const uint2 gv2 = *reinterpret_cast<const uint2*>(&gt[grow * 264 + mi * 16 + q * 4]);
        const float4 w2v = *reinterpret_cast<const float4*>(&w2s[mi * 16 + q * 4]);
        float y0 = acc[0] + blo(gv2.x);
        float y1 = acc[1] + bhi(gv2.x);
        float y2 = acc[2] + blo(gv2.y);
        float y3 = acc[3] + bhi(gv2.y);
        s += (y0 > 0.f ? y0 : 0.f) * w2v.x;
        s += (y1 > 0.f ? y1 : 0.f) * w2v.y;
        s += (y2 > 0.f ? y2 : 0.f) * w2v.z;
        s += (y3 > 0.f ? y3 : 0.f) * w2v.w;
    }
    s += __shfl_xor(s, 16);
    s += __shfl_xor(s, 32);
    int eg = base + grow;
    if (q == 0 && eg < P)
        out[eg] = logexp[eg] + b2[0] + s;
}

// ---------------- launch ----------------

extern "C" void kernel_launch(void* const* d_in, const int* in_sizes, int n_in,
                              void* d_out, int out_size, void* d_ws, size_t ws_size,
                              hipStream_t stream) {
    const float* x      = (const float*)d_in[0];
    const int*   eidx   = (const int*)d_in[1];
    const int*   eu     = (const int*)d_in[2];
    const int*   ev     = (const int*)d_in[3];
    const float* attr   = (const float*)d_in[4];
    const float* logexp = (const float*)d_in[5];
    const float* Wl1    = (const float*)d_in[6];
    const float* bl1    = (const float*)d_in[7];
    const float* Wr1    = (const float*)d_in[8];
    const float* Wl2    = (const float*)d_in[9];
    const float* bl2    = (const float*)d_in[10];
    const float* Wr2    = (const float*)d_in[11];
    const float* W1     = (const float*)d_in[12];
    const float* b1     = (const float*)d_in[13];
    const float* W2     = (const float*)d_in[14];
    const float* b2     = (const float*)d_in[15];
    float* out = (float*)d_out;

    const int N = in_sizes[0] / 128;
    const int E = in_sizes[1] / 2;
    const int P = in_sizes[2];
    const int* src = eidx;
    const int* dst = eidx + E;

    char* ws = (char*)d_ws;
    size_t off = 0;
    auto alloc = [&](size_t bytes) -> void* {
        off = (off + 255) & ~(size_t)255;
        void* p = ws + off;
        off += bytes;
        return p;
    };
    int* row_ptr = (int*)alloc((size_t)(N + 1) * 4);
    int* cursor  = (int*)alloc((size_t)N * 4);
    int* bucket  = (int*)alloc((size_t)E * 4);
    unsigned short* h1 = (unsigned short*)alloc((size_t)N * 256 * 2);
    unsigned short* h2 = (unsigned short*)alloc((size_t)N * 256 * 2);
    char* shared_base = (char*)alloc((size_t)N * 512 * 2);
    unsigned short* xb   = (unsigned short*)shared_base;                         // N*128
    unsigned short* agg1 = (unsigned short*)(shared_base + (size_t)N * 128 * 2); // N*128
    unsigned short* agg2 = (unsigned short*)(shared_base + (size_t)N * 256 * 2); // N*256
    unsigned short* G2   = (unsigned short*)shared_base;                         // N*512
    unsigned short* Wc1  = (unsigned short*)alloc((size_t)65536 * 2);
    unsigned short* Wc2  = (unsigned short*)alloc((size_t)131072 * 2);
    unsigned short* W1g  = (unsigned short*)alloc((size_t)131072 * 2);
    unsigned short* WaF  = (unsigned short*)alloc((size_t)8192 * 2);

    hipMemsetAsync(cursor, 0, (size_t)N * 4, stream);
    k_count<<<(E + 255) / 256, 256, 0, stream>>>(dst, cursor, E);
    k_scan<<<1, 1024, 0, stream>>>(cursor, row_ptr, N);
    k_scatter<<<(E + 255) / 256, 256, 0, stream>>>(src, dst, cursor, bucket, E);
    k_convert_weights<<<(65536 + 131072 + 131072 + 8192 + 255) / 256, 256, 0, stream>>>(
        Wl1, Wr1, Wl2, Wr2, W1, b1, Wc1, Wc2, W1g, WaF);
    k_f2b_copy<<<(N * 128 + 255) / 256, 256, 0, stream>>>(x, xb, N * 128);

    k_agg_x<<<(N + 3) / 4, 256, 0, stream>>>(xb, row_ptr, bucket, agg1, N);
    dim3 gconv((N + 127) / 128, 2);
    k_conv_gemm<<<gconv, 256, 0, stream>>>(agg1, xb, Wc1, bl1, h1, N, 128);
    k_agg_h<<<(N + 3) / 4, 256, 0, stream>>>(h1, row_ptr, bucket, agg2, N);
    k_conv_gemm<<<gconv, 256, 0, stream>>>(agg2, h1, Wc2, bl2, h2, N, 256);

    dim3 gg((N + 127) / 128, 4);
    k_gemm_g<<<gg, 256, 0, stream>>>(h2, W1g, G2, N);
    k_edge<<<(P + 63) / 64, 256, 0, stream>>>(G2, attr, eu, ev, (const uint4*)WaF,
                                              W2, b2, logexp, out, P);
}